// Round 10
// baseline (175.334 us; speedup 1.0000x reference)
//
#include <hip/hip_runtime.h>

#define NPIX 524288
#define DH 22
#define NHID 11
#define TPB 256
#define WTILE (64*DH)     // 1408 floats = per-wave tile (contiguous in global layout)

typedef float f32x4 __attribute__((ext_vector_type(4)));
typedef float f32x2 __attribute__((ext_vector_type(2)));

// input-chunk boundaries for the 4-way wave stagger
__device__ __constant__ const int ISPLIT[5] = {0, 6, 12, 17, 22};

__device__ __forceinline__ void activate(float* h) {
#pragma unroll
    for (int j = 15; j < 19; ++j) h[j] = __expf(-h[j]*h[j]) * 2.0f - 1.0f;
    h[21] = __sinf(h[21]);
}

__device__ __forceinline__ void write_tile(float* __restrict__ wlds,
                                           const float* __restrict__ h, int lane) {
    f32x2* d = (f32x2*)(wlds + lane * DH);
#pragma unroll
    for (int k = 0; k < 11; ++k) { f32x2 v = { h[2*k], h[2*k+1] }; d[k] = v; }
}

// read wave-private tile (linear, conflict-free) -> NT dwordx4 burst
__device__ __forceinline__ void flush_tile(float* __restrict__ gwave,
                                           const float* __restrict__ wlds, int lane) {
    const f32x4* s4 = (const f32x4*)wlds;   // 352 float4 slots
    f32x4* g4 = (f32x4*)gwave;
#pragma unroll
    for (int k = 0; k < 5; ++k) {
        const int s = lane + 64 * k;
        __builtin_nontemporal_store(s4[s], &g4[s]);
    }
    if (lane < 32) {
        const int s = 320 + lane;
        __builtin_nontemporal_store(s4[s], &g4[s]);
    }
}

__global__ __launch_bounds__(256) void cppn_main(const float* __restrict__ xin,
                                                 const float* __restrict__ Win,
                                                 const float* __restrict__ Whid,
                                                 const float* __restrict__ Wout,
                                                 float* __restrict__ out) {
    __shared__ float lds[4][WTILE];   // wave-private regions; no __syncthreads anywhere
    const int t    = threadIdx.x;
    const int w    = t >> 6;          // wave id 0..3 -> stagger slot
    const int lane = t & 63;
    const int blk  = blockIdx.x;
    const int p    = blk * TPB + t;
    float* wlds = lds[w];

    const f32x4 xv = ((const f32x4*)xin)[p];
    __builtin_nontemporal_store(xv, &((f32x4*)(out + (size_t)3 * NPIX))[p]);  // x chunk

    // ---- layer 0: x[4] @ w_in[4,22] (wave-uniform weights -> s_load) ----
    float h[DH];
#pragma unroll
    for (int o = 0; o < DH; ++o) {
        float a =      xv.x * Win[0*DH + o];
        a = fmaf(xv.y, Win[1*DH + o], a);
        a = fmaf(xv.z, Win[2*DH + o], a);
        a = fmaf(xv.w, Win[3*DH + o], a);
        h[o] = a;
    }
    activate(h);
    write_tile(wlds, h, lane);        // tile 0 staged

    float* hwave = out + (size_t)7 * NPIX + (size_t)blk * (TPB * DH) + w * WTILE;
    const size_t chunk = (size_t)NPIX * DH;

    // ---- hidden layers; tile-l flush staggered by wave id inside layer-(l+1) FMAs ----
    for (int l = 0; l < NHID; ++l) {
        const float* W = Whid + (size_t)l * DH * DH;
        float hn[DH];
#pragma unroll
        for (int o = 0; o < DH; ++o) hn[o] = 0.0f;
#pragma unroll
        for (int c = 0; c < 4; ++c) {
            if (c == w) flush_tile(hwave + (size_t)l * chunk, wlds, lane);  // uniform branch
#pragma unroll
            for (int i = ISPLIT[c]; i < ISPLIT[c+1]; ++i) {
                const float hi = h[i];
#pragma unroll
                for (int o = 0; o < DH; ++o)
                    hn[o] = fmaf(hi, W[i*DH + o], hn[o]);
            }
        }
        activate(hn);
#pragma unroll
        for (int o = 0; o < DH; ++o) h[o] = hn[o];
        write_tile(wlds, h, lane);    // tile l+1 (own flush already done: in-wave order)
    }

    // ---- tile 11 flush staggered inside the out-projection ----
    float o0 = 0.0f, o1 = 0.0f, o2 = 0.0f;
#pragma unroll
    for (int c = 0; c < 4; ++c) {
        if (c == w) flush_tile(hwave + (size_t)NHID * chunk, wlds, lane);
#pragma unroll
        for (int d = ISPLIT[c]; d < ISPLIT[c+1]; ++d) {
            o0 = fmaf(h[d], Wout[d*3 + 0], o0);
            o1 = fmaf(h[d], Wout[d*3 + 1], o1);
            o2 = fmaf(h[d], Wout[d*3 + 2], o2);
        }
    }

    // per-wave stage [64 x 3] (192 floats = 48 float4), store to both out chunks
    wlds[lane*3 + 0] = o0; wlds[lane*3 + 1] = o1; wlds[lane*3 + 2] = o2;
    if (lane < 48) {
        const f32x4 v = ((const f32x4*)wlds)[lane];
        const size_t s = (size_t)blk * 192 + w * 48 + lane;   // float4 index
        __builtin_nontemporal_store(v, &((f32x4*)out)[s]);                        // first chunk
        __builtin_nontemporal_store(v, &((f32x4*)(out + (size_t)271 * NPIX))[s]); // last chunk
    }
}

extern "C" void kernel_launch(void* const* d_in, const int* in_sizes, int n_in,
                              void* d_out, int out_size, void* d_ws, size_t ws_size,
                              hipStream_t stream) {
    const float* x     = (const float*)d_in[0];
    const float* w_in  = (const float*)d_in[1];
    const float* w_hid = (const float*)d_in[2];
    const float* w_out = (const float*)d_in[3];
    float* o = (float*)d_out;

    cppn_main<<<NPIX / TPB, TPB, 0, stream>>>(x, w_in, w_hid, w_out, o);
}

// Round 11
// 123.388 us; speedup vs baseline: 1.4210x; 1.4210x over previous
//
#include <hip/hip_runtime.h>

#define NPIX 524288
#define DH 22
#define NHID 11
#define TPB 128
#define NWAVE (TPB/64)
#define WTILE (64*DH)     // 1408 floats = per-wave tile (contiguous in global layout)

typedef float f32x4 __attribute__((ext_vector_type(4)));
typedef float f32x2 __attribute__((ext_vector_type(2)));

__device__ __forceinline__ void activate(float* h) {
#pragma unroll
    for (int j = 15; j < 19; ++j) h[j] = __expf(-h[j]*h[j]) * 2.0f - 1.0f;
    h[21] = __sinf(h[21]);
}

__device__ __forceinline__ void hidden_layer(float* __restrict__ h,
                                             const float* __restrict__ W) {
    float hn[DH];
#pragma unroll
    for (int o = 0; o < DH; ++o) hn[o] = 0.0f;
#pragma unroll
    for (int i = 0; i < DH; ++i) {
        const float hi = h[i];
#pragma unroll
        for (int o = 0; o < DH; ++o)
            hn[o] = fmaf(hi, W[i*DH + o], hn[o]);
    }
    activate(hn);
#pragma unroll
    for (int o = 0; o < DH; ++o) h[o] = hn[o];
}

// Wave-private staging, no __syncthreads. Wave owns 64 pixels whose h-features
// are CONTIGUOUS (1408 floats) in each global chunk.
// write: 11 ds_write_b64 word-stride 22; read: linear ds_read_b128 ->
// nontemporal global_store_dwordx4 (NT is +48% vs plain, r7 vs r8).
__device__ __forceinline__ void flush_h(float* __restrict__ gwave,
                                        const float* __restrict__ h,
                                        float* __restrict__ wlds, int lane) {
    f32x2* d = (f32x2*)(wlds + lane * DH);
#pragma unroll
    for (int k = 0; k < 11; ++k) { f32x2 v2 = { h[2*k], h[2*k+1] }; d[k] = v2; }
    const f32x4* s4 = (const f32x4*)wlds;   // 352 float4 slots
    f32x4* g4 = (f32x4*)gwave;
#pragma unroll
    for (int k = 0; k < 5; ++k) {
        const int s = lane + 64 * k;
        __builtin_nontemporal_store(s4[s], &g4[s]);
    }
    if (lane < 32) {
        const int s = 320 + lane;
        __builtin_nontemporal_store(s4[s], &g4[s]);
    }
}

__global__ __launch_bounds__(TPB) void cppn_main(const float* __restrict__ xin,
                                                 const float* __restrict__ Win,
                                                 const float* __restrict__ Whid,
                                                 const float* __restrict__ Wout,
                                                 float* __restrict__ out) {
    __shared__ float lds[NWAVE][WTILE];   // wave-private regions
    const int t    = threadIdx.x;
    const int w    = t >> 6;
    const int lane = t & 63;
    const int blk  = blockIdx.x;
    const int p    = blk * TPB + t;
    float* wlds = lds[w];

    const f32x4 xv = ((const f32x4*)xin)[p];
    __builtin_nontemporal_store(xv, &((f32x4*)(out + (size_t)3 * NPIX))[p]);  // x chunk

    // ---- layer 0: x[4] @ w_in[4,22] (wave-uniform weights -> s_load) ----
    float h[DH];
#pragma unroll
    for (int o = 0; o < DH; ++o) {
        float a =      xv.x * Win[0*DH + o];
        a = fmaf(xv.y, Win[1*DH + o], a);
        a = fmaf(xv.z, Win[2*DH + o], a);
        a = fmaf(xv.w, Win[3*DH + o], a);
        h[o] = a;
    }
    activate(h);

    // h-chunk base for this wave
    float* hwave = out + (size_t)7 * NPIX + (size_t)blk * (TPB * DH) + w * WTILE;
    const size_t chunk = (size_t)NPIX * DH;

    flush_h(hwave, h, wlds, lane);
    for (int l = 0; l < NHID; ++l) {
        hidden_layer(h, Whid + (size_t)l * DH * DH);
        flush_h(hwave + (size_t)(l + 1) * chunk, h, wlds, lane);
    }

    // ---- output projection: h11[22] @ w_out[22,3] ----
    float o0 = 0.0f, o1 = 0.0f, o2 = 0.0f;
#pragma unroll
    for (int d = 0; d < DH; ++d) {
        o0 = fmaf(h[d], Wout[d*3 + 0], o0);
        o1 = fmaf(h[d], Wout[d*3 + 1], o1);
        o2 = fmaf(h[d], Wout[d*3 + 2], o2);
    }
    // per-wave stage [64 x 3] (192 floats = 48 float4), store to both out chunks
    wlds[lane*3 + 0] = o0; wlds[lane*3 + 1] = o1; wlds[lane*3 + 2] = o2;
    if (lane < 48) {
        const f32x4 v = ((const f32x4*)wlds)[lane];
        const size_t s = (size_t)blk * (TPB/4*3) + w * 48 + lane;   // float4 index
        __builtin_nontemporal_store(v, &((f32x4*)out)[s]);                        // first chunk
        __builtin_nontemporal_store(v, &((f32x4*)(out + (size_t)271 * NPIX))[s]); // last chunk
    }
}

extern "C" void kernel_launch(void* const* d_in, const int* in_sizes, int n_in,
                              void* d_out, int out_size, void* d_ws, size_t ws_size,
                              hipStream_t stream) {
    const float* x     = (const float*)d_in[0];
    const float* w_in  = (const float*)d_in[1];
    const float* w_hid = (const float*)d_in[2];
    const float* w_out = (const float*)d_in[3];
    float* o = (float*)d_out;

    cppn_main<<<NPIX / TPB, TPB, 0, stream>>>(x, w_in, w_hid, w_out, o);
}